// Round 1
// baseline (694.879 us; speedup 1.0000x reference)
//
#include <hip/hip_runtime.h>
#include <hip/hip_bf16.h>

// GCN 2-layer. With prescaled rows h'[v]=dinv[v]*h[v]:
//   agg[v] = dinv[v]*(h'[v] + sum_e h'[src_e]) + b
// CSR via bucket-binned counting sort (bucket-local rowptr/dinv).
// GEMMs via bf16 MFMA 16x16x32, epilogue scales by dinv and stores bf16.
// Aggregation: XCD-sliced. Feature dim split into 8 slices of 16 dims
// (3.2 MB/slice fits one XCD's 4 MB L2). blockIdx%8 -> XCD (round-robin
// dispatch) pins slice c to XCD c, cutting per-XCD compulsory gather
// fill from 8x25.6 MB to 1x25.6 MB total.

#define D 128
#define BUKBITS 7          // 128 nodes per bucket
#define BUKSZ 128
#define MAXBUK 1024        // supports N <= 131072 (src < 2^25 packing)
#define SCHUNK 16384       // edges per scatter/hist block

#define NSLICE 8           // feature slices == XCDs
#define AGG_BLOCKS 2048    // 8 blocks/CU * 256 CUs, all co-resident
#define WAVES_PER_SLICE 1024  // (AGG_BLOCKS/NSLICE) * 4 waves

typedef __attribute__((ext_vector_type(8))) short short8;
typedef __attribute__((ext_vector_type(4))) float f32x4;

static __device__ __forceinline__ ushort f2b(float f) {
    __hip_bfloat16 h = __float2bfloat16(f);
    return *reinterpret_cast<ushort*>(&h);
}

// ---------------- CSR build ----------------

__global__ __launch_bounds__(256) void k_bukhist(const int* __restrict__ dst, int* __restrict__ bukcnt,
                                                 int E, int nbuk) {
    __shared__ int lh[MAXBUK];
    for (int i = threadIdx.x; i < nbuk; i += 256) lh[i] = 0;
    __syncthreads();
    int start = blockIdx.x * SCHUNK;
    int end = min(E, start + SCHUNK);
    for (int e = start + threadIdx.x; e < end; e += 256)
        atomicAdd(&lh[dst[e] >> BUKBITS], 1);
    __syncthreads();
    for (int i = threadIdx.x; i < nbuk; i += 256)
        if (lh[i]) atomicAdd(&bukcnt[i], lh[i]);
}

__global__ __launch_bounds__(256) void k_bukscan(const int* __restrict__ bukcnt, int* __restrict__ bukbase,
                                                 int* __restrict__ gcur, int nbuk, int E) {
    __shared__ int vals[MAXBUK];
    __shared__ int tsum[256];
    int t = threadIdx.x;
    for (int i = t; i < MAXBUK; i += 256) vals[i] = (i < nbuk) ? bukcnt[i] : 0;
    __syncthreads();
    int o = t * 4;
    int s = vals[o] + vals[o + 1] + vals[o + 2] + vals[o + 3];
    tsum[t] = s;
    __syncthreads();
    for (int off = 1; off < 256; off <<= 1) {
        int v = (t >= off) ? tsum[t - off] : 0;
        __syncthreads();
        tsum[t] += v;
        __syncthreads();
    }
    int run = tsum[t] - s;
    for (int i = 0; i < 4; i++) {
        int idx = o + i;
        if (idx < nbuk) { bukbase[idx] = run; gcur[idx] = run; }
        run += vals[idx];
    }
    if (t == 0) bukbase[nbuk] = E;
}

// edges -> bucket-grouped tmp: (dstLow << 25) | src
__global__ __launch_bounds__(256) void k_scatter(const int* __restrict__ src, const int* __restrict__ dst,
                                                 int* __restrict__ gcur, uint* __restrict__ tmp,
                                                 int E, int nbuk) {
    __shared__ int lh[MAXBUK];
    __shared__ int lbase[MAXBUK];
    for (int i = threadIdx.x; i < nbuk; i += 256) lh[i] = 0;
    __syncthreads();
    int start = blockIdx.x * SCHUNK;
    int end = min(E, start + SCHUNK);
    for (int e = start + threadIdx.x; e < end; e += 256)
        atomicAdd(&lh[dst[e] >> BUKBITS], 1);
    __syncthreads();
    for (int i = threadIdx.x; i < nbuk; i += 256) {
        int c = lh[i];
        lbase[i] = c ? atomicAdd(&gcur[i], c) : 0;
        lh[i] = 0;
    }
    __syncthreads();
    for (int e = start + threadIdx.x; e < end; e += 256) {
        int s = src[e];
        int d = dst[e];
        int bk = d >> BUKBITS;
        int r = atomicAdd(&lh[bk], 1);
        tmp[lbase[bk] + r] = ((uint)(d & (BUKSZ - 1)) << 25) | (uint)s;
    }
}

// bucket-local: per-node count, LDS scan -> rowptr+dinv, place eord
__global__ __launch_bounds__(256) void k_fillC(const uint* __restrict__ tmp, const int* __restrict__ bukbase,
                                               int* __restrict__ eord, int* __restrict__ rowptr,
                                               float* __restrict__ dinv, int n, int nbuk) {
    __shared__ int cnt[BUKSZ];
    __shared__ int sc[BUKSZ];
    __shared__ int lrp[BUKSZ];
    int b = blockIdx.x;
    int node0 = b << BUKBITS;
    int nn = min(BUKSZ, n - node0);
    int e0 = bukbase[b], e1 = bukbase[b + 1];
    int t = threadIdx.x;
    if (t < BUKSZ) cnt[t] = 0;
    __syncthreads();
    for (int e = e0 + t; e < e1; e += 256)
        atomicAdd(&cnt[tmp[e] >> 25], 1);
    __syncthreads();
    int c0 = (t < BUKSZ) ? cnt[t] : 0;
    if (t < BUKSZ) sc[t] = c0;
    __syncthreads();
    for (int off = 1; off < BUKSZ; off <<= 1) {
        int v = (t < BUKSZ && t >= off) ? sc[t - off] : 0;
        __syncthreads();
        if (t < BUKSZ) sc[t] += v;
        __syncthreads();
    }
    if (t < BUKSZ) lrp[t] = e0 + sc[t] - c0;
    if (t < nn) {
        rowptr[node0 + t] = e0 + sc[t] - c0;
        dinv[node0 + t] = 1.0f / sqrtf((float)(c0 + 1));  // +1 self-loop
    }
    if (b == nbuk - 1 && t == 0) rowptr[n] = e1;
    __syncthreads();
    if (t < BUKSZ) cnt[t] = 0;
    __syncthreads();
    for (int e = e0 + t; e < e1; e += 256) {
        uint u = tmp[e];
        int dL = (int)(u >> 25);
        int s = (int)(u & 0x1FFFFFFu);
        int r = atomicAdd(&cnt[dL], 1);
        eord[lrp[dL] + r] = s;
    }
}

// ---------------- W prep: transpose + bf16 (Wt[n][k]) ----------------
__global__ __launch_bounds__(256) void k_prepW(const float* __restrict__ W1, const float* __restrict__ W2,
                                               ushort* __restrict__ Wt1, ushort* __restrict__ Wt2) {
    int i = blockIdx.x * 256 + threadIdx.x;
    if (i < 16384) {
        int kk = i >> 7, nn = i & 127;
        Wt1[nn * 128 + kk] = f2b(W1[i]);
        Wt2[nn * 128 + kk] = f2b(W2[i]);
    }
}

// ---------------- MFMA GEMM: Hb[row] = bf16(dinv[row] * (X[row] @ W)) ----------------
// A fp32 (layer1) or bf16 (layer2). Layouts (verified):
// A[m=lane&15][k=quad*8+j]; B[k][n=lane&15]; D col=lane&15, row=quad*4+r
template <bool ABF16>
__global__ __launch_bounds__(256) void k_gemm(const void* __restrict__ Xv, const ushort* __restrict__ Wt,
                                              const float* __restrict__ dinv, ushort* __restrict__ Hb,
                                              int nrows) {
    const int wave = threadIdx.x >> 6;
    const int lane = threadIdx.x & 63;
    const int quad = lane >> 4;
    const int m = lane & 15;
    const int row0 = blockIdx.x * 64 + wave * 16;
    const int rowc = min(row0 + m, nrows - 1);

    f32x4 acc[8];
    #pragma unroll
    for (int t = 0; t < 8; t++) acc[t] = (f32x4){0.f, 0.f, 0.f, 0.f};

    #pragma unroll
    for (int ks = 0; ks < 4; ks++) {
        const int k0 = ks * 32 + quad * 8;
        short8 a;
        if (ABF16) {
            a = *(const short8*)((const ushort*)Xv + (size_t)rowc * D + k0);
        } else {
            const float* p = (const float*)Xv + (size_t)rowc * D + k0;
            float4 u0 = ((const float4*)p)[0];
            float4 u1 = ((const float4*)p)[1];
            a[0] = (short)f2b(u0.x); a[1] = (short)f2b(u0.y);
            a[2] = (short)f2b(u0.z); a[3] = (short)f2b(u0.w);
            a[4] = (short)f2b(u1.x); a[5] = (short)f2b(u1.y);
            a[6] = (short)f2b(u1.z); a[7] = (short)f2b(u1.w);
        }
        #pragma unroll
        for (int t = 0; t < 8; t++) {
            short8 b = *(const short8*)(Wt + ((t * 16 + m) * D + k0));
            acc[t] = __builtin_amdgcn_mfma_f32_16x16x32_bf16(a, b, acc[t], 0, 0, 0);
        }
    }
    #pragma unroll
    for (int r = 0; r < 4; r++) {
        int orow = row0 + quad * 4 + r;
        if (orow < nrows) {
            float dvv = dinv[orow];
            #pragma unroll
            for (int t = 0; t < 8; t++)
                Hb[(size_t)orow * D + t * 16 + m] = f2b(acc[t][r] * dvv);
        }
    }
}

// ---------------- XCD-sliced CSR aggregation ----------------
// out[v] = dv*(h'[v]+sum h'[s]) + b, feature dims split into NSLICE slices
// of 16 dims (8 dwords). Block b handles slice b%8 (-> XCD b%8 under
// round-robin dispatch); the 3.2 MB Hb slice stays resident in that XCD's
// 4 MB L2. Within a wave: 64 lanes = 8 edges x 8 dwords; butterfly reduce
// over the 8 edge-groups; lanes 0..7 write the node's slice chunk.
template <bool RELU, bool OBF16>
__global__ __launch_bounds__(256, 8) void k_agg_slice(const ushort* __restrict__ Hb,
                                                      const float* __restrict__ dinv,
                                                      const int* __restrict__ rowptr,
                                                      const int* __restrict__ eord,
                                                      const float* __restrict__ bias,
                                                      void* __restrict__ outp, int n) {
    const int slice = blockIdx.x & (NSLICE - 1);
    const int blk = blockIdx.x >> 3;                      // block index within slice
    const int wid = (blk << 2) + (threadIdx.x >> 6);      // wave index within slice [0,1024)
    const int lane = threadIdx.x & 63;
    const int g = lane >> 3;                              // edge subgroup 0..7
    const int w = lane & 7;                               // dword within slice 0..7
    const int cofs = slice * 8 + w;                       // dword offset within 64-dword row
    const uint* __restrict__ Hu = (const uint*)Hb;
    const float2 bb = ((const float2*)bias)[cofs];

    for (int v = wid; v < n; v += WAVES_PER_SLICE) {
        float ax = 0.f, ay = 0.f;
        int e = rowptr[v];
        const int end = rowptr[v + 1];
        for (; e + 15 < end; e += 16) {
            int s0 = eord[e + g];
            int s1 = eord[e + 8 + g];
            uint h0 = Hu[(size_t)s0 * 64 + cofs];
            uint h1 = Hu[(size_t)s1 * 64 + cofs];
            ax += __uint_as_float(h0 << 16) + __uint_as_float(h1 << 16);
            ay += __uint_as_float(h0 & 0xffff0000u) + __uint_as_float(h1 & 0xffff0000u);
        }
        for (; e + 7 < end; e += 8) {
            int s0 = eord[e + g];
            uint h0 = Hu[(size_t)s0 * 64 + cofs];
            ax += __uint_as_float(h0 << 16);
            ay += __uint_as_float(h0 & 0xffff0000u);
        }
        if (e + g < end) {
            int s0 = eord[e + g];
            uint h0 = Hu[(size_t)s0 * 64 + cofs];
            ax += __uint_as_float(h0 << 16);
            ay += __uint_as_float(h0 & 0xffff0000u);
        }
        // reduce across the 8 edge-groups (lanes with equal lane&7)
        ax += __shfl_xor(ax, 8);  ay += __shfl_xor(ay, 8);
        ax += __shfl_xor(ax, 16); ay += __shfl_xor(ay, 16);
        ax += __shfl_xor(ax, 32); ay += __shfl_xor(ay, 32);
        if (lane < 8) {
            uint hs = Hu[(size_t)v * 64 + cofs];           // self-loop term
            float dv = dinv[v];
            float rx = dv * (ax + __uint_as_float(hs << 16)) + bb.x;
            float ry = dv * (ay + __uint_as_float(hs & 0xffff0000u)) + bb.y;
            if (RELU) { rx = fmaxf(rx, 0.f); ry = fmaxf(ry, 0.f); }
            if (OBF16) {
                ((uint*)outp)[(size_t)v * 64 + cofs] = ((uint)f2b(ry) << 16) | (uint)f2b(rx);
            } else {
                ((float2*)outp)[(size_t)v * 64 + cofs] = make_float2(rx, ry);
            }
        }
    }
}

// ---------------- launcher ----------------

static inline size_t alignup(size_t x) { return (x + 511) & ~(size_t)511; }

extern "C" void kernel_launch(void* const* d_in, const int* in_sizes, int n_in,
                              void* d_out, int out_size, void* d_ws, size_t ws_size,
                              hipStream_t stream) {
    const float* x  = (const float*)d_in[0];
    const int* eidx = (const int*)d_in[1];   // [2,E]: src row, dst row (int32)
    const float* W1 = (const float*)d_in[2];
    const float* b1 = (const float*)d_in[3];
    const float* W2 = (const float*)d_in[4];
    const float* b2 = (const float*)d_in[5];
    float* out = (float*)d_out;

    const int N = in_sizes[0] / D;
    const int E = in_sizes[1] / 2;
    const int* src = eidx;
    const int* dst = eidx + E;
    const int nbuk = (N + BUKSZ - 1) >> BUKBITS;   // 782

    // workspace
    char* ws = (char*)d_ws;
    size_t off = 0;
    int* bukcnt = (int*)(ws + off);   off = alignup(off + (size_t)MAXBUK * 4);
    int* bukbase = (int*)(ws + off);  off = alignup(off + (size_t)(MAXBUK + 1) * 4);
    int* gcur   = (int*)(ws + off);   off = alignup(off + (size_t)MAXBUK * 4);
    int* rowptr = (int*)(ws + off);   off = alignup(off + (size_t)(N + 1) * 4);
    float* dinv = (float*)(ws + off); off = alignup(off + (size_t)N * 4);
    int* eord   = (int*)(ws + off);   off = alignup(off + (size_t)E * 4);
    ushort* hbuf = (ushort*)(ws + off); off = alignup(off + (size_t)N * D * 2);
    ushort* act  = (ushort*)(ws + off); off = alignup(off + (size_t)N * D * 2);
    ushort* Wt1 = (ushort*)(ws + off); off = alignup(off + 16384 * 2);
    ushort* Wt2 = (ushort*)(ws + off); off = alignup(off + 16384 * 2);
    uint* tmp = (uint*)hbuf;  // E uints (6.4 MB) alias hbuf; dead before gemm1 writes
    (void)ws_size;

    const int nT = 256;
    const int gChunk = (E + SCHUNK - 1) / SCHUNK;   // 98

    hipMemsetAsync(bukcnt, 0, (size_t)MAXBUK * 4, stream);
    k_prepW<<<64, nT, 0, stream>>>(W1, W2, Wt1, Wt2);
    k_bukhist<<<gChunk, nT, 0, stream>>>(dst, bukcnt, E, nbuk);
    k_bukscan<<<1, nT, 0, stream>>>(bukcnt, bukbase, gcur, nbuk, E);
    k_scatter<<<gChunk, nT, 0, stream>>>(src, dst, gcur, tmp, E, nbuk);
    k_fillC<<<nbuk, nT, 0, stream>>>(tmp, bukbase, eord, rowptr, dinv, N, nbuk);

    const int gGemm = (N + 63) / 64;

    // layer 1: hbuf = bf16(dinv*(x @ W1)); act(bf16) = relu(agg + b1)
    k_gemm<false><<<gGemm, nT, 0, stream>>>((const void*)x, Wt1, dinv, hbuf, N);
    k_agg_slice<true, true><<<AGG_BLOCKS, nT, 0, stream>>>(hbuf, dinv, rowptr, eord, b1, (void*)act, N);

    // layer 2: hbuf = bf16(dinv*(act @ W2)); out(fp32) = agg + b2
    k_gemm<true><<<gGemm, nT, 0, stream>>>((const void*)act, Wt2, dinv, hbuf, N);
    k_agg_slice<false, false><<<AGG_BLOCKS, nT, 0, stream>>>(hbuf, dinv, rowptr, eord, b2, (void*)out, N);
}